// Round 3
// baseline (546.368 us; speedup 1.0000x reference)
//
#include <hip/hip_runtime.h>

#define N_ 16
#define V_ 16384
#define D_ 128
#define E_ 65536
#define L_ 2
#define M_ (N_*V_)   // 262144 rows

typedef __attribute__((ext_vector_type(8))) short short8;
typedef __attribute__((ext_vector_type(4))) float floatx4;

__device__ inline unsigned short f2bf(float x){
  unsigned u = __builtin_bit_cast(unsigned, x);
  unsigned r = u + 0x7fffu + ((u >> 16) & 1u);
  return (unsigned short)(r >> 16);
}
__device__ inline float bf2f(unsigned short h){
  unsigned u = ((unsigned)h) << 16;
  return __builtin_bit_cast(float, u);
}
__device__ inline unsigned pack2(float a, float b){
  return (unsigned)f2bf(a) | ((unsigned)f2bf(b) << 16);
}

// ---- weights fp32 -> bf16 in MFMA frag-major layout [l][mat][ks][ct][lane][8] ----
__global__ __launch_bounds__(256) void conv_w_k(const float* __restrict__ Wself,
                                                const float* __restrict__ Wnei,
                                                unsigned short* __restrict__ Wb){
  int f = blockIdx.x * 256 + threadIdx.x;          // 0..8191 frags
  int lane = f & 63;
  int ct   = (f >> 6) & 7;
  int ks   = (f >> 9) & 3;
  int mat  = (f >> 11) & 1;
  int l    = (f >> 12) & 1;
  int e = ct * 16 + (lane & 15);
  int d = ks * 32 + (lane >> 4) * 8;
  const float* src = (mat ? Wnei : Wself) + ((size_t)l * D_ * D_ + e * D_ + d);
  uint4 o;
  o.x = pack2(src[0], src[1]);
  o.y = pack2(src[2], src[3]);
  o.z = pack2(src[4], src[5]);
  o.w = pack2(src[6], src[7]);
  ((uint4*)Wb)[f] = o;
}

// ---- CSR build ----
__global__ __launch_bounds__(256) void hist_k(const int* __restrict__ dst, int* __restrict__ cnt){
  int e = blockIdx.x * 256 + threadIdx.x;
  atomicAdd(&cnt[dst[e]], 1);
}

__global__ __launch_bounds__(256) void scan_k(const int* __restrict__ cnt, int* __restrict__ row_ptr){
  __shared__ int part[256];
  int t = threadIdx.x;
  int base = t * 64;
  int s = 0;
  for (int i = 0; i < 64; ++i) s += cnt[base + i];
  part[t] = s;
  __syncthreads();
  for (int d = 1; d < 256; d <<= 1){
    int v = (t >= d) ? part[t - d] : 0;
    __syncthreads();
    part[t] += v;
    __syncthreads();
  }
  int off = part[t] - s;   // exclusive prefix
  for (int i = 0; i < 64; ++i){
    row_ptr[base + i] = off;
    off += cnt[base + i];
  }
  if (t == 255) row_ptr[V_] = off;
}

__global__ __launch_bounds__(256) void scatter_k(const int* __restrict__ src,
                                                 const int* __restrict__ dst,
                                                 const float* __restrict__ vals,
                                                 const int* __restrict__ row_ptr,
                                                 int* __restrict__ fill,
                                                 int* __restrict__ csr_col,
                                                 float* __restrict__ csr_val){
  int e = blockIdx.x * 256 + threadIdx.x;
  int d = dst[e];
  int pos = row_ptr[d] + atomicAdd(&fill[d], 1);
  csr_col[pos] = src[e];
  csr_val[pos] = vals[e];
}

// ---- Fused SpMM+GEMM: Y = A_self*Ws^T + (Anorm@A_self... gathered)*Wn^T
//      MODE 0: inputs from fp32 H, no norm. MODE 1: inputs from bf16 Y0, apply
//      relu(x*sc+sh) to both self rows and gathered rows.
//      A_nei is accumulated in registers directly in MFMA A-frag layout
//      (no LDS round trip, no global Xnei tensor). ----
template<int MODE>
__global__ __launch_bounds__(256, 2) void gemmf_k(const float* __restrict__ Hf,
                                                  const unsigned short* __restrict__ Xb,
                                                  const int* __restrict__ row_ptr,
                                                  const int* __restrict__ csr_col,
                                                  const float* __restrict__ csr_val,
                                                  const uint4* __restrict__ Wfrag,
                                                  const float* __restrict__ scsh,
                                                  unsigned short* __restrict__ Yb,
                                                  float* __restrict__ stats){
  __shared__ uint4 lds_w[4096];                     // 64 KB: [mat][ks][ct][lane]
  __shared__ float lds_s[256];
  int tid = threadIdx.x;
  for (int i = tid; i < 4096; i += 256) lds_w[i] = Wfrag[i];
  if (MODE) lds_s[tid] = scsh[tid];
  __syncthreads();

  int wave = tid >> 6, lane = tid & 63;
  int quad = lane >> 4, l15 = lane & 15;
  int row0 = blockIdx.x * 128 + wave * 32;          // 128-row block never crosses n
  int n    = row0 >> 14;                            // row0 / V_
  int vb   = row0 & (V_ - 1);
  const short8* lw = (const short8*)lds_w;

  // per-column BN scale/shift for this lane's 8-col groups (MODE 1 only)
  float scv[4][8], shv[4][8];
  if (MODE){
#pragma unroll
    for (int ks = 0; ks < 4; ++ks)
#pragma unroll
      for (int j = 0; j < 8; ++j){
        int c = ks * 32 + quad * 8 + j;
        scv[ks][j] = lds_s[c];
        shv[ks][j] = lds_s[128 + c];
      }
  }

  floatx4 zero = {0.f, 0.f, 0.f, 0.f};
  floatx4 acc[2][8];
#pragma unroll
  for (int rt = 0; rt < 2; ++rt)
#pragma unroll
    for (int ct = 0; ct < 8; ++ct) acc[rt][ct] = zero;

#pragma unroll
  for (int rt = 0; rt < 2; ++rt){
    size_t r = (size_t)(row0 + rt * 16 + l15);
    int v = vb + rt * 16 + l15;

    // ---- A_self fragments ----
    short8 a_s[4];
    if (MODE == 0){
      const float* src = Hf + r * 128 + quad * 8;
#pragma unroll
      for (int ks = 0; ks < 4; ++ks){
        float4 f0 = *(const float4*)(src + ks * 32);
        float4 f1 = *(const float4*)(src + ks * 32 + 4);
        short8 t;
        t[0] = (short)f2bf(f0.x); t[1] = (short)f2bf(f0.y);
        t[2] = (short)f2bf(f0.z); t[3] = (short)f2bf(f0.w);
        t[4] = (short)f2bf(f1.x); t[5] = (short)f2bf(f1.y);
        t[6] = (short)f2bf(f1.z); t[7] = (short)f2bf(f1.w);
        a_s[ks] = t;
      }
    } else {
      const unsigned short* src = Xb + r * 128 + quad * 8;
#pragma unroll
      for (int ks = 0; ks < 4; ++ks){
        short8 raw = *(const short8*)(src + ks * 32);
        short8 t;
#pragma unroll
        for (int j = 0; j < 8; ++j){
          float x = bf2f((unsigned short)raw[j]);
          x = fmaxf(0.f, x * scv[ks][j] + shv[ks][j]);
          t[j] = (short)f2bf(x);
        }
        a_s[ks] = t;
      }
    }

    // ---- gather A_nei directly into frag-layout registers ----
    float accn[4][8];
#pragma unroll
    for (int ks = 0; ks < 4; ++ks)
#pragma unroll
      for (int j = 0; j < 8; ++j) accn[ks][j] = 0.f;

    int e0 = row_ptr[v], e1 = row_ptr[v + 1];
    for (int i = e0; i < e1; i += 4){
      int cc[4]; float aa[4];
#pragma unroll
      for (int j = 0; j < 4; ++j){
        int idx = (i + j < e1) ? (i + j) : (e1 - 1);
        cc[j] = csr_col[idx];
        aa[j] = (i + j < e1) ? csr_val[idx] : 0.f;
      }
#pragma unroll
      for (int j = 0; j < 4; ++j){
        if (MODE == 0){
          const float* xr = Hf + ((size_t)n * V_ + cc[j]) * 128 + quad * 8;
#pragma unroll
          for (int ks = 0; ks < 4; ++ks){
            float4 f0 = *(const float4*)(xr + ks * 32);
            float4 f1 = *(const float4*)(xr + ks * 32 + 4);
            accn[ks][0] += aa[j] * f0.x; accn[ks][1] += aa[j] * f0.y;
            accn[ks][2] += aa[j] * f0.z; accn[ks][3] += aa[j] * f0.w;
            accn[ks][4] += aa[j] * f1.x; accn[ks][5] += aa[j] * f1.y;
            accn[ks][6] += aa[j] * f1.z; accn[ks][7] += aa[j] * f1.w;
          }
        } else {
          const unsigned short* xr = Xb + ((size_t)n * V_ + cc[j]) * 128 + quad * 8;
#pragma unroll
          for (int ks = 0; ks < 4; ++ks){
            short8 w = *(const short8*)(xr + ks * 32);
#pragma unroll
            for (int jj = 0; jj < 8; ++jj){
              float x = bf2f((unsigned short)w[jj]);
              x = fmaxf(0.f, x * scv[ks][jj] + shv[ks][jj]);
              accn[ks][jj] += aa[j] * x;
            }
          }
        }
      }
    }
    short8 a_n[4];
#pragma unroll
    for (int ks = 0; ks < 4; ++ks){
      short8 t;
#pragma unroll
      for (int j = 0; j < 8; ++j) t[j] = (short)f2bf(accn[ks][j]);
      a_n[ks] = t;
    }

    // ---- MFMA ----
#pragma unroll
    for (int ks = 0; ks < 4; ++ks){
#pragma unroll
      for (int ct = 0; ct < 8; ++ct){
        short8 bs = lw[((0 * 4 + ks) * 8 + ct) * 64 + lane];
        short8 bn = lw[((1 * 4 + ks) * 8 + ct) * 64 + lane];
        acc[rt][ct] = __builtin_amdgcn_mfma_f32_16x16x32_bf16(a_s[ks], bs, acc[rt][ct], 0, 0, 0);
        acc[rt][ct] = __builtin_amdgcn_mfma_f32_16x16x32_bf16(a_n[ks], bn, acc[rt][ct], 0, 0, 0);
      }
    }
  }

  // ---- epilogue: bf16 Y store (C layout: col=lane&15, row=quad*4+reg) + BN stats ----
  float* sum_base = stats;            // [64][128]
  float* sq_base  = stats + 64 * 128; // [64][128]
  int slot = blockIdx.x & 63;
#pragma unroll
  for (int rt = 0; rt < 2; ++rt){
    int rowq = row0 + rt * 16 + quad * 4;
#pragma unroll
    for (int ct = 0; ct < 8; ++ct){
      int col = ct * 16 + l15;
      float s = 0.f, q = 0.f;
#pragma unroll
      for (int rg = 0; rg < 4; ++rg){
        float yv = acc[rt][ct][rg];
        Yb[(size_t)(rowq + rg) * 128 + col] = f2bf(yv);
        s += yv; q += yv * yv;
      }
      s += __shfl_xor(s, 16); s += __shfl_xor(s, 32);
      q += __shfl_xor(q, 16); q += __shfl_xor(q, 32);
      if (lane < 16)      atomicAdd(&sum_base[slot * 128 + ct * 16 + lane], s);
      else if (lane < 32) atomicAdd(&sq_base [slot * 128 + ct * 16 + (lane & 15)], q);
    }
  }
}

// ---- reduce stats -> scale/shift ----
__global__ __launch_bounds__(128) void finalize_k(const float* __restrict__ stats,
                                                  const float* __restrict__ gamma,
                                                  const float* __restrict__ beta,
                                                  float* __restrict__ scsh){
  int d = threadIdx.x;
  float s = 0.f, q = 0.f;
  for (int k = 0; k < 64; ++k){
    s += stats[k * 128 + d];
    q += stats[64 * 128 + k * 128 + d];
  }
  float inv = 1.0f / (float)M_;
  float mean = s * inv;
  float var  = q * inv - mean * mean;
  float rstd = rsqrtf(var + 1e-5f);
  float scale = gamma[d] * rstd;
  scsh[d]       = scale;
  scsh[128 + d] = beta[d] - mean * scale;
}

// ---- final BN apply + ReLU: Y bf16 -> fp32 d_out ----
__global__ __launch_bounds__(256) void bn_out_k(const uint4* __restrict__ Y,
                                                const float* __restrict__ scsh,
                                                float4* __restrict__ out){
  int i = blockIdx.x * 256 + threadIdx.x;          // 8 elems
  int c = (i * 8) & 127;
  uint4 y = Y[i];
  float4 sc0 = *(const float4*)(scsh + c);
  float4 sc1 = *(const float4*)(scsh + c + 4);
  float4 sh0 = *(const float4*)(scsh + 128 + c);
  float4 sh1 = *(const float4*)(scsh + 132 + c);
  float4 o0, o1;
  o0.x = fmaxf(0.f, bf2f((unsigned short)(y.x & 0xffff)) * sc0.x + sh0.x);
  o0.y = fmaxf(0.f, bf2f((unsigned short)(y.x >> 16))    * sc0.y + sh0.y);
  o0.z = fmaxf(0.f, bf2f((unsigned short)(y.y & 0xffff)) * sc0.z + sh0.z);
  o0.w = fmaxf(0.f, bf2f((unsigned short)(y.y >> 16))    * sc0.w + sh0.w);
  o1.x = fmaxf(0.f, bf2f((unsigned short)(y.z & 0xffff)) * sc1.x + sh1.x);
  o1.y = fmaxf(0.f, bf2f((unsigned short)(y.z >> 16))    * sc1.y + sh1.y);
  o1.z = fmaxf(0.f, bf2f((unsigned short)(y.w & 0xffff)) * sc1.z + sh1.z);
  o1.w = fmaxf(0.f, bf2f((unsigned short)(y.w >> 16))    * sc1.w + sh1.w);
  out[2 * i]     = o0;
  out[2 * i + 1] = o1;
}

static inline size_t align_up(size_t x, size_t a){ return (x + a - 1) & ~(a - 1); }

extern "C" void kernel_launch(void* const* d_in, const int* in_sizes, int n_in,
                              void* d_out, int out_size, void* d_ws, size_t ws_size,
                              hipStream_t stream){
  const float* H     = (const float*)d_in[0];
  const int*   esrc  = (const int*)  d_in[1];
  const int*   edst  = (const int*)  d_in[2];
  const float* avals = (const float*)d_in[3];
  const float* Wself = (const float*)d_in[4];
  const float* Wnei  = (const float*)d_in[5];
  const float* gamma = (const float*)d_in[6];
  const float* beta  = (const float*)d_in[7];

  char* ws = (char*)d_ws;
  size_t off = 0;
  unsigned short* Y0 = (unsigned short*)(ws + off); off += align_up((size_t)M_ * D_ * 2, 256);
  unsigned short* Y1 = (unsigned short*)(ws + off); off += align_up((size_t)M_ * D_ * 2, 256);
  unsigned short* Wb = (unsigned short*)(ws + off); off += align_up((size_t)L_ * 2 * D_ * D_ * 2, 256);
  int*   row_ptr = (int*)  (ws + off); off += align_up((size_t)(V_ + 1) * 4, 256);
  int*   csr_col = (int*)  (ws + off); off += align_up((size_t)E_ * 4, 256);
  float* csr_val = (float*)(ws + off); off += align_up((size_t)E_ * 4, 256);
  float* scsh0   = (float*)(ws + off); off += align_up((size_t)2 * 128 * 4, 256);
  float* scsh1   = (float*)(ws + off); off += align_up((size_t)2 * 128 * 4, 256);
  // contiguous zeroed region: cnt | fill | stats0 | stats1
  char* zbase = ws + off;
  int*   cnt    = (int*)  (ws + off); off += (size_t)V_ * 4;
  int*   fill   = (int*)  (ws + off); off += (size_t)V_ * 4;
  float* stats0 = (float*)(ws + off); off += (size_t)64 * 128 * 2 * 4;
  float* stats1 = (float*)(ws + off); off += (size_t)64 * 128 * 2 * 4;
  size_t zbytes = (size_t)(ws + off - zbase);
  (void)ws_size; (void)in_sizes; (void)n_in; (void)out_size;

  conv_w_k<<<8192 / 256, 256, 0, stream>>>(Wself, Wnei, Wb);
  hipMemsetAsync(zbase, 0, zbytes, stream);
  hist_k<<<E_ / 256, 256, 0, stream>>>(edst, cnt);
  scan_k<<<1, 256, 0, stream>>>(cnt, row_ptr);
  scatter_k<<<E_ / 256, 256, 0, stream>>>(esrc, edst, avals, row_ptr, fill, csr_col, csr_val);

  // ---- layer 0 (reads fp32 H directly; SpMM fused into GEMM) ----
  gemmf_k<0><<<M_ / 128, 256, 0, stream>>>(H, nullptr, row_ptr, csr_col, csr_val,
                                           (const uint4*)Wb, nullptr, Y0, stats0);
  finalize_k<<<1, 128, 0, stream>>>(stats0, gamma, beta, scsh0);

  // ---- layer 1 (BN+ReLU of layer 0 fused into self/gather reads) ----
  gemmf_k<1><<<M_ / 128, 256, 0, stream>>>(nullptr, Y0, row_ptr, csr_col, csr_val,
                                           (const uint4*)Wb + 4096, scsh0, Y1, stats1);
  finalize_k<<<1, 128, 0, stream>>>(stats1, gamma + 128, beta + 128, scsh1);
  bn_out_k<<<M_ * D_ / 8 / 256, 256, 0, stream>>>((const uint4*)Y1, scsh1, (float4*)d_out);
}